// Round 16
// baseline (134.797 us; speedup 1.0000x reference)
//
#include <hip/hip_runtime.h>
#include <cmath>

#define TABLE_SZ 16384
#define NLEV 16
#define BLOCK 512
#define PPT 2

typedef float v2f __attribute__((ext_vector_type(2)));

struct ResArr { float r[NLEV]; };

// ---------------- prologue: tables f32 -> packed fp16x2 (RNE) ---------------
__global__ __launch_bounds__(256) void cvt_tables(
    const float* __restrict__ src, uint32_t* __restrict__ dst, int n_entries)
{
    int i = blockIdx.x * blockDim.x + threadIdx.x;
    int e = i * 4;
    if (e + 3 < n_entries) {
        const float4* s4 = (const float4*)(src) + i * 2;
        float4 a = s4[0], b = s4[1];
        float v[8] = {a.x,a.y,a.z,a.w,b.x,b.y,b.z,b.w};
        uint32_t o[4];
        #pragma unroll
        for (int k = 0; k < 4; ++k) {
            unsigned short lo = __builtin_bit_cast(unsigned short, (_Float16)v[2*k+0]);
            unsigned short hi = __builtin_bit_cast(unsigned short, (_Float16)v[2*k+1]);
            o[k] = (uint32_t)lo | ((uint32_t)hi << 16);
        }
        *(uint4*)(dst + e) = make_uint4(o[0], o[1], o[2], o[3]);
    }
}

// ---------------- helpers ----------------------------------------------------
template <int TBLOCK>
__device__ __forceinline__ void stage_h(const uint32_t* __restrict__ tb, int l,
                                        uint32_t* buf, int tid, int wid)
{
    const char* gbase = (const char*)tb + (size_t)l * (TABLE_SZ * 4);
    #pragma unroll
    for (int j = 0; j < (TABLE_SZ * 4) / (TBLOCK * 16); ++j) {
        uint32_t goff = (uint32_t)(j * (TBLOCK * 16) + tid * 16);
        uint32_t loff = (uint32_t)(j * (TBLOCK * 16) + wid * 1024);
        __builtin_amdgcn_global_load_lds(
            (const __attribute__((address_space(1))) uint32_t*)(gbase + goff),
            (__attribute__((address_space(3))) uint32_t*)((char*)buf + loff),
            16, 0, 0);
    }
}

struct C8 { uint32_t h[8]; };
// high = ceil (NOT low+1); low = trunc (sp in [0,512) >= 0).
// Strength-reduced: P*hy = P*ly + (hy!=ly ? P : 0).
__device__ __forceinline__ C8 corner_idx(float r, float px, float py, float pz)
{
    const uint32_t P1 = 2654435761u, P2 = 805459861u;
    const uint32_t m  = TABLE_SZ - 1u;
    float sx = r*px, sy = r*py, sz = r*pz;
    uint32_t lx = (uint32_t)sx,  hx = (uint32_t)ceilf(sx);
    uint32_t ly = (uint32_t)sy,  hy = (uint32_t)ceilf(sy);
    uint32_t lz = (uint32_t)sz,  hz = (uint32_t)ceilf(sz);
    uint32_t yl = P1*ly;
    uint32_t yh = (hy == ly) ? yl : yl + P1;
    uint32_t zl = P2*lz;
    uint32_t zh = (hz == lz) ? zl : zl + P2;
    C8 c;
    c.h[0] = (lx ^ yl ^ zl) & m;
    c.h[1] = (hx ^ yl ^ zl) & m;
    c.h[2] = (hx ^ yh ^ zl) & m;
    c.h[3] = (lx ^ yh ^ zl) & m;
    c.h[4] = (lx ^ yl ^ zh) & m;
    c.h[5] = (hx ^ yl ^ zh) & m;
    c.h[6] = (hx ^ yh ^ zh) & m;
    c.h[7] = (lx ^ yh ^ zh) & m;
    return c;
}

// x in [0,1): w = x - floor(x) == x exactly (faithful). cw per point:
// product order (x*y)*z, corners v0..v7, k-ascending accumulation.
__device__ __forceinline__ float2 level_accum_h(const uint32_t* tab, float r,
                                                float px, float py, float pz,
                                                const float* cw)
{
    C8 c = corner_idx(r, px, py, pz);
    uint32_t vv[8];
    #pragma unroll
    for (int k = 0; k < 8; ++k) vv[k] = tab[c.h[k]];
    float a0 = 0.f, a1 = 0.f;
    #pragma unroll
    for (int k = 0; k < 8; ++k) {
        _Float16 lo = __builtin_bit_cast(_Float16, (unsigned short)(vv[k] & 0xFFFFu));
        _Float16 hi = __builtin_bit_cast(_Float16, (unsigned short)(vv[k] >> 16));
        a0 += (float)lo * cw[k];
        a1 += (float)hi * cw[k];
    }
    return make_float2(a0, a1);
}

// Issue 8 asm-pinned TA-pipe gathers (f32 table). Order is pinned: volatile
// asm maintains program order vs the barriers and stage builtins (fenced).
__device__ __forceinline__ void ta_issue(const v2f* __restrict__ t, float r,
                                         float px, float py, float pz, v2f* g)
{
    C8 c = corner_idx(r, px, py, pz);
    #pragma unroll
    for (int kk = 0; kk < 8; ++kk) {
        const v2f* p = t + c.h[kk];
        asm volatile("global_load_dwordx2 %0, %1, off"
                     : "=&v"(g[kk]) : "v"(p) : "memory");
    }
}

// -------- main kernel: 14 LDS levels (0..12,14) + 2 TA levels (13,15) -------
// Iter k: LDS level lev(k)= k<13 ? k : 14.  Head: stage lev(k+1) -> buf^1;
// counted vmcnt (per-wave: stage=8 instr, TA=16 instr in queue):
//   k=9,12: vmcnt(24); k=10: vmcnt(8) (ALSO drains TA13 after 2-iter flight);
//   k=13: vmcnt(0); else vmcnt(8).  Then s_barrier; consume parked TA
// (keep-alive asm anchors the reads after the drain); LDS gather; window
// flushes; TA issues at tails (k=8 -> L13, k=11 -> L15); end barrier.
__global__ __launch_bounds__(BLOCK) void mrhe_ta(
    const float* __restrict__ x,
    const v2f* __restrict__ ftab,     // original f32 tables (TA levels)
    const uint32_t* __restrict__ tb,  // packed fp16x2 tables (LDS levels)
    float* __restrict__ out,
    ResArr res, int B)
{
    __shared__ uint32_t tab[2][TABLE_SZ];   // 2 x 64 KiB

    const int tid  = threadIdx.x;
    const int wid  = tid >> 6;
    const int base = blockIdx.x * (BLOCK * PPT);

    float px[PPT], py[PPT], pz[PPT];
    float cw[PPT][8];
    #pragma unroll
    for (int p = 0; p < PPT; ++p) {
        int idx = base + p * BLOCK + tid;
        size_t j = (idx < B) ? (size_t)idx : 0;
        px[p] = x[3*j+0]; py[p] = x[3*j+1]; pz[p] = x[3*j+2];
        float ax = 1.0f - px[p], ay = 1.0f - py[p], az = 1.0f - pz[p];
        cw[p][0] = (ax*ay)*az;          cw[p][1] = (px[p]*ay)*az;
        cw[p][2] = (px[p]*py[p])*az;    cw[p][3] = (ax*py[p])*az;
        cw[p][4] = (ax*ay)*pz[p];       cw[p][5] = (px[p]*ay)*pz[p];
        cw[p][6] = (px[p]*py[p])*pz[p]; cw[p][7] = (ax*py[p])*pz[p];
    }

    asm volatile("" ::: "memory");
    stage_h<BLOCK>(tb, 0, tab[0], tid, wid);   // prologue: level 0 -> buf 0
    asm volatile("" ::: "memory");

    float o[PPT][16];         // current 64B window — static indexing only
    v2f g13[PPT][8], g15[PPT][8];

    #pragma unroll
    for (int k = 0; k < 14; ++k) {
        const int lev = (k < 13) ? k : 14;

        if (k < 13) {
            const int nl = (k + 1 < 13) ? (k + 1) : 14;
            asm volatile("" ::: "memory");
            stage_h<BLOCK>(tb, nl, tab[(k + 1) & 1], tid, wid);
            asm volatile("" ::: "memory");
        }

        if (k == 9 || k == 12)
            asm volatile("s_waitcnt vmcnt(24)" ::: "memory");
        else if (k == 13)
            asm volatile("s_waitcnt vmcnt(0)" ::: "memory");
        else
            asm volatile("s_waitcnt vmcnt(8)" ::: "memory");
        __builtin_amdgcn_sched_barrier(0);
        asm volatile("s_barrier" ::: "memory");

        if (k == 11) {   // consume TA level 13 (drained by k=10's vmcnt(8))
            #pragma unroll
            for (int p = 0; p < PPT; ++p) {
                float b0 = 0.f, b1 = 0.f;
                #pragma unroll
                for (int kk = 0; kk < 8; ++kk) {
                    asm volatile("" : "+v"(g13[p][kk]));   // anchor after drain
                    b0 += g13[p][kk].x * cw[p][kk];
                    b1 += g13[p][kk].y * cw[p][kk];
                }
                o[p][10] = b0; o[p][11] = b1;              // level-13 slots
            }
        }
        if (k == 13) {   // consume TA level 15 (drained by vmcnt(0))
            #pragma unroll
            for (int p = 0; p < PPT; ++p) {
                float b0 = 0.f, b1 = 0.f;
                #pragma unroll
                for (int kk = 0; kk < 8; ++kk) {
                    asm volatile("" : "+v"(g15[p][kk]));
                    b0 += g15[p][kk].x * cw[p][kk];
                    b1 += g15[p][kk].y * cw[p][kk];
                }
                o[p][14] = b0; o[p][15] = b1;              // level-15 slots
            }
        }

        // ---- LDS gather for level lev ----
        {
            const uint32_t* buf = tab[k & 1];
            #pragma unroll
            for (int p = 0; p < PPT; ++p) {
                float2 a = level_accum_h(buf, res.r[lev], px[p], py[p], pz[p], cw[p]);
                o[p][2*(lev & 7) + 0] = a.x;
                o[p][2*(lev & 7) + 1] = a.y;
            }
        }

        if (k == 7) {    // flush window0: levels 0..7 (full 64 B sector)
            #pragma unroll
            for (int p = 0; p < PPT; ++p) {
                int idx = base + p * BLOCK + tid;
                if (idx < B) {
                    float* po = out + (size_t)idx * (2*NLEV);
                    #pragma unroll
                    for (int q = 0; q < 4; ++q) {
                        float4 v;
                        v.x = o[p][4*q+0]; v.y = o[p][4*q+1];
                        v.z = o[p][4*q+2]; v.w = o[p][4*q+3];
                        ((float4*)po)[q] = v;
                    }
                }
            }
        }

        if (k == 8) {    // issue TA level 13 (consumed at k=11)
            #pragma unroll
            for (int p = 0; p < PPT; ++p)
                ta_issue(ftab + (size_t)13 * TABLE_SZ, res.r[13],
                         px[p], py[p], pz[p], g13[p]);
        }
        if (k == 11) {   // issue TA level 15 (consumed at k=13)
            #pragma unroll
            for (int p = 0; p < PPT; ++p)
                ta_issue(ftab + (size_t)15 * TABLE_SZ, res.r[15],
                         px[p], py[p], pz[p], g15[p]);
        }

        asm volatile("s_barrier" ::: "memory");   // protect buf before reuse
    }

    // flush window1: levels 8..15 (full 64 B sector)
    #pragma unroll
    for (int p = 0; p < PPT; ++p) {
        int idx = base + p * BLOCK + tid;
        if (idx < B) {
            float* po = out + (size_t)idx * (2*NLEV) + 16;
            #pragma unroll
            for (int q = 0; q < 4; ++q) {
                float4 v;
                v.x = o[p][4*q+0]; v.y = o[p][4*q+1];
                v.z = o[p][4*q+2]; v.w = o[p][4*q+3];
                ((float4*)po)[q] = v;
            }
        }
    }
}

// -------- fallback: r15's proven pure-LDS kernel (109 us) -------------------
template <int TBLOCK, int TPPT>
__global__ __launch_bounds__(TBLOCK) void mrhe_db(
    const float* __restrict__ x,
    const uint32_t* __restrict__ tb,
    float* __restrict__ out,
    ResArr res, int B)
{
    __shared__ uint32_t tab[2][TABLE_SZ];

    const int tid  = threadIdx.x;
    const int wid  = tid >> 6;
    const int base = blockIdx.x * (TBLOCK * TPPT);

    float px[TPPT], py[TPPT], pz[TPPT];
    float cw[TPPT][8];
    #pragma unroll
    for (int p = 0; p < TPPT; ++p) {
        int idx = base + p * TBLOCK + tid;
        size_t j = (idx < B) ? (size_t)idx : 0;
        px[p] = x[3*j+0]; py[p] = x[3*j+1]; pz[p] = x[3*j+2];
        float ax = 1.0f - px[p], ay = 1.0f - py[p], az = 1.0f - pz[p];
        cw[p][0] = (ax*ay)*az;          cw[p][1] = (px[p]*ay)*az;
        cw[p][2] = (px[p]*py[p])*az;    cw[p][3] = (ax*py[p])*az;
        cw[p][4] = (ax*ay)*pz[p];       cw[p][5] = (px[p]*ay)*pz[p];
        cw[p][6] = (px[p]*py[p])*pz[p]; cw[p][7] = (ax*py[p])*pz[p];
    }

    stage_h<TBLOCK>(tb, 0, tab[0], tid, wid);

    float o[TPPT][16];

    #pragma unroll
    for (int l = 0; l < NLEV; ++l) {
        if (l + 1 < NLEV) {
            stage_h<TBLOCK>(tb, l + 1, tab[(l + 1) & 1], tid, wid);
            asm volatile("s_waitcnt vmcnt(8)" ::: "memory");
        } else {
            asm volatile("s_waitcnt vmcnt(0)" ::: "memory");
        }
        asm volatile("s_barrier" ::: "memory");

        const uint32_t* buf = tab[l & 1];
        #pragma unroll
        for (int p = 0; p < TPPT; ++p) {
            float2 a = level_accum_h(buf, res.r[l], px[p], py[p], pz[p], cw[p]);
            o[p][2*(l & 7) + 0] = a.x;
            o[p][2*(l & 7) + 1] = a.y;
        }

        if ((l & 7) == 7) {
            const int half = l >> 3;
            #pragma unroll
            for (int p = 0; p < TPPT; ++p) {
                int idx = base + p * TBLOCK + tid;
                if (idx < B) {
                    float* po = out + (size_t)idx * (2*NLEV) + half * 16;
                    #pragma unroll
                    for (int q = 0; q < 4; ++q) {
                        float4 v;
                        v.x = o[p][4*q+0]; v.y = o[p][4*q+1];
                        v.z = o[p][4*q+2]; v.w = o[p][4*q+3];
                        ((float4*)po)[q] = v;
                    }
                }
            }
        }

        asm volatile("s_barrier" ::: "memory");
    }
}

// ---- safe no-workspace fallback: direct global gather ----------------------
__global__ __launch_bounds__(256) void mrhe_direct(
    const float* __restrict__ x,
    const float* __restrict__ tables,
    float* __restrict__ out,
    ResArr res, int B)
{
    int i = blockIdx.x * blockDim.x + threadIdx.x;
    if (i >= B) return;
    float px = x[3*(size_t)i+0], py = x[3*(size_t)i+1], pz = x[3*(size_t)i+2];
    float ax = 1.0f - px, ay = 1.0f - py, az = 1.0f - pz;
    float cw[8] = {(ax*ay)*az,(px*ay)*az,(px*py)*az,(ax*py)*az,
                   (ax*ay)*pz,(px*ay)*pz,(px*py)*pz,(ax*py)*pz};
    float o[2*NLEV];
    #pragma unroll
    for (int l = 0; l < NLEV; ++l) {
        C8 c = corner_idx(res.r[l], px, py, pz);
        const float2* tbl = (const float2*)tables + (size_t)l * TABLE_SZ;
        float a0 = 0.f, a1 = 0.f;
        #pragma unroll
        for (int k = 0; k < 8; ++k) {
            float2 f = tbl[c.h[k]];
            a0 += f.x * cw[k]; a1 += f.y * cw[k];
        }
        o[2*l+0] = a0; o[2*l+1] = a1;
    }
    float4* po = (float4*)(out + (size_t)i * (2*NLEV));
    #pragma unroll
    for (int q = 0; q < (2*NLEV)/4; ++q) {
        float4 v; v.x = o[4*q+0]; v.y = o[4*q+1]; v.z = o[4*q+2]; v.w = o[4*q+3];
        po[q] = v;
    }
}

extern "C" void kernel_launch(void* const* d_in, const int* in_sizes, int n_in,
                              void* d_out, int out_size, void* d_ws, size_t ws_size,
                              hipStream_t stream)
{
    const float* x      = (const float*)d_in[0];
    const float* tables = (const float*)d_in[1];
    float* out = (float*)d_out;
    int B = in_sizes[0] / 3;

    // b = exp((log(512)-log(16))/15); res_l = floor(16 * b**l)  (host libm)
    ResArr res;
    float bgrow = expf((logf(512.0f) - logf(16.0f)) / 15.0f);
    for (int l = 0; l < NLEV; ++l)
        res.r[l] = floorf(16.0f * powf(bgrow, (float)l));

    const int n_entries = NLEV * TABLE_SZ;
    const size_t need = (size_t)n_entries * 4;          // 1 MiB packed fp16x2

    if (ws_size >= need && d_ws) {
        uint32_t* tb = (uint32_t*)d_ws;
        hipLaunchKernelGGL(cvt_tables, dim3(n_entries/4/256), dim3(256), 0, stream,
                           tables, tb, n_entries);

        hipFuncAttributes attr{};
        hipError_t e = hipFuncGetAttributes(&attr, (const void*)mrhe_ta);
        bool useTa = (e == hipSuccess) && (attr.localSizeBytes == 0);

        if (useTa) {
            int per_block = BLOCK * PPT;
            int grid = (B + per_block - 1) / per_block;
            hipLaunchKernelGGL(mrhe_ta, dim3(grid), dim3(BLOCK), 0, stream,
                               x, (const v2f*)tables, tb, out, res, B);
        } else {
            int per_block = 512 * 2;
            int grid = (B + per_block - 1) / per_block;
            hipLaunchKernelGGL((mrhe_db<512, 2>), dim3(grid), dim3(512), 0, stream,
                               x, tb, out, res, B);
        }
    } else {
        int grid = (B + 255) / 256;
        hipLaunchKernelGGL(mrhe_direct, dim3(grid), dim3(256), 0, stream,
                           x, tables, out, res, B);
    }
}

// Round 17
// 109.140 us; speedup vs baseline: 1.2351x; 1.2351x over previous
//
#include <hip/hip_runtime.h>
#include <cmath>

#define TABLE_SZ 16384
#define NLEV 16

struct ResArr { float r[NLEV]; };

// ---------------- prologue: tables f32 -> packed fp16x2 (RNE) ---------------
// fp16 on ~1e-4 values: abs err <= 6e-8 (better than bf16's 2e-7); f32->f16
// cast is RNE; f16->f32 on consume is exact (denormals included).
__global__ __launch_bounds__(256) void cvt_tables(
    const float* __restrict__ src, uint32_t* __restrict__ dst, int n_entries)
{
    int i = blockIdx.x * blockDim.x + threadIdx.x;   // 4 entries per thread
    int e = i * 4;
    if (e + 3 < n_entries) {
        const float4* s4 = (const float4*)(src) + i * 2;
        float4 a = s4[0], b = s4[1];
        float v[8] = {a.x,a.y,a.z,a.w,b.x,b.y,b.z,b.w};
        uint32_t o[4];
        #pragma unroll
        for (int k = 0; k < 4; ++k) {
            unsigned short lo = __builtin_bit_cast(unsigned short, (_Float16)v[2*k+0]);
            unsigned short hi = __builtin_bit_cast(unsigned short, (_Float16)v[2*k+1]);
            o[k] = (uint32_t)lo | ((uint32_t)hi << 16);   // lo=feat0, hi=feat1
        }
        *(uint4*)(dst + e) = make_uint4(o[0], o[1], o[2], o[3]);
    }
}

// ---------------- helpers ----------------------------------------------------
template <int TBLOCK>
__device__ __forceinline__ void stage_h(const uint32_t* __restrict__ tb, int l,
                                        uint32_t* buf, int tid, int wid)
{
    const char* gbase = (const char*)tb + (size_t)l * (TABLE_SZ * 4);
    #pragma unroll
    for (int j = 0; j < (TABLE_SZ * 4) / (TBLOCK * 16); ++j) {
        uint32_t goff = (uint32_t)(j * (TBLOCK * 16) + tid * 16);   // per-lane
        uint32_t loff = (uint32_t)(j * (TBLOCK * 16) + wid * 1024); // wave-uniform
        __builtin_amdgcn_global_load_lds(
            (const __attribute__((address_space(1))) uint32_t*)(gbase + goff),
            (__attribute__((address_space(3))) uint32_t*)((char*)buf + loff),
            16, 0, 0);
    }
}

// x in [0,1): interp weight w = x - floor(x) == x exactly, so coords double as
// trilinear weights (faithful). cw precomputed per point: product order
// (x*y)*z, corners v0..v7, k-ascending accumulation.
// high = ceil (NOT low+1); low = trunc (sp in [0,512) >= 0).
// Strength reduction: P*hy = P*ly + (hy!=ly ? P : 0).
__device__ __forceinline__ float2 level_accum_h(const uint32_t* tab, float r,
                                                float px, float py, float pz,
                                                const float* cw)
{
    const uint32_t P1 = 2654435761u, P2 = 805459861u;
    const uint32_t m  = TABLE_SZ - 1u;

    float sx = r*px, sy = r*py, sz = r*pz;
    uint32_t lx = (uint32_t)sx,  hx = (uint32_t)ceilf(sx);
    uint32_t ly = (uint32_t)sy,  hy = (uint32_t)ceilf(sy);
    uint32_t lz = (uint32_t)sz,  hz = (uint32_t)ceilf(sz);
    uint32_t yl = P1*ly;
    uint32_t yh = (hy == ly) ? yl : yl + P1;
    uint32_t zl = P2*lz;
    uint32_t zh = (hz == lz) ? zl : zl + P2;

    uint32_t h0 = (lx ^ yl ^ zl) & m;
    uint32_t h1 = (hx ^ yl ^ zl) & m;
    uint32_t h2 = (hx ^ yh ^ zl) & m;
    uint32_t h3 = (lx ^ yh ^ zl) & m;
    uint32_t h4 = (lx ^ yl ^ zh) & m;
    uint32_t h5 = (hx ^ yl ^ zh) & m;
    uint32_t h6 = (hx ^ yh ^ zh) & m;
    uint32_t h7 = (lx ^ yh ^ zh) & m;

    uint32_t v0 = tab[h0], v1 = tab[h1], v2 = tab[h2], v3 = tab[h3];
    uint32_t v4 = tab[h4], v5 = tab[h5], v6 = tab[h6], v7 = tab[h7];

    float a0 = 0.f, a1 = 0.f;
    uint32_t vv[8] = {v0,v1,v2,v3,v4,v5,v6,v7};
    #pragma unroll
    for (int k = 0; k < 8; ++k) {
        _Float16 lo = __builtin_bit_cast(_Float16, (unsigned short)(vv[k] & 0xFFFFu));
        _Float16 hi = __builtin_bit_cast(_Float16, (unsigned short)(vv[k] >> 16));
        a0 += (float)lo * cw[k];    // -> v_fma_mix_f32 (f16 src folded)
        a1 += (float)hi * cw[k];
    }
    return make_float2(a0, a1);
}

// -------- main kernel: double-buffered fp16 staging, counted vmcnt ----------
// Per level l: issue DMA for l+1 into buf^1; s_waitcnt vmcnt(R) (level-l's R
// loads are the OLDER entries; vmem retires in order); raw s_barrier; gather
// level l overlapping l+1's DMA; end barrier protects buf reuse. NEVER
// __syncthreads() in the loop (drains vmcnt to 0).
//
// STRUCTURAL CEILING (r12-r16 evidence): DS-pipe-throughput-bound at ~108 us.
// 8192 random wave64 gathers/CU x ~28 cyc + staging ds-writes = ~260K cyc.
// Null results: waves/SIMD 2->4 (r13), VALU -30% (r15). Negative: TA-pipe
// offload of 5 levels (r14: +58%) and 2 levels deep-lagged (r16: +24%).
template <int TBLOCK, int TPPT>
__global__ __launch_bounds__(TBLOCK) void mrhe_db(
    const float* __restrict__ x,
    const uint32_t* __restrict__ tb,
    float* __restrict__ out,
    ResArr res, int B)
{
    constexpr int ROUNDS = (TABLE_SZ * 4) / (TBLOCK * 16);
    static_assert(ROUNDS == 8 || ROUNDS == 16, "vmcnt literal must match");

    __shared__ uint32_t tab[2][TABLE_SZ];   // 2 x 64 KiB

    const int tid  = threadIdx.x;
    const int wid  = tid >> 6;
    const int base = blockIdx.x * (TBLOCK * TPPT);

    float px[TPPT], py[TPPT], pz[TPPT];
    float cw[TPPT][8];                 // level-invariant corner weights
    #pragma unroll
    for (int p = 0; p < TPPT; ++p) {
        int idx = base + p * TBLOCK + tid;
        size_t j = (idx < B) ? (size_t)idx : 0;
        px[p] = x[3*j+0]; py[p] = x[3*j+1]; pz[p] = x[3*j+2];
        float ax = 1.0f - px[p], ay = 1.0f - py[p], az = 1.0f - pz[p];
        cw[p][0] = (ax*ay)*az;          cw[p][1] = (px[p]*ay)*az;
        cw[p][2] = (px[p]*py[p])*az;    cw[p][3] = (ax*py[p])*az;
        cw[p][4] = (ax*ay)*pz[p];       cw[p][5] = (px[p]*ay)*pz[p];
        cw[p][6] = (px[p]*py[p])*pz[p]; cw[p][7] = (ax*py[p])*pz[p];
    }

    stage_h<TBLOCK>(tb, 0, tab[0], tid, wid);   // prologue: level 0 -> buf 0

    float o[TPPT][16];   // current 64B window — statically indexed only

    #pragma unroll
    for (int l = 0; l < NLEV; ++l) {
        if (l + 1 < NLEV) {
            stage_h<TBLOCK>(tb, l + 1, tab[(l + 1) & 1], tid, wid);
            if constexpr (ROUNDS == 8)
                asm volatile("s_waitcnt vmcnt(8)" ::: "memory");
            else
                asm volatile("s_waitcnt vmcnt(16)" ::: "memory");
        } else {
            asm volatile("s_waitcnt vmcnt(0)" ::: "memory");
        }
        asm volatile("s_barrier" ::: "memory");   // level-l DMA visible to all

        const uint32_t* buf = tab[l & 1];
        #pragma unroll
        for (int p = 0; p < TPPT; ++p) {
            float2 a = level_accum_h(buf, res.r[l], px[p], py[p], pz[p], cw[p]);
            o[p][2*(l & 7) + 0] = a.x;
            o[p][2*(l & 7) + 1] = a.y;
        }

        if ((l & 7) == 7) {
            // 64 contiguous 64B-aligned bytes per point (full sectors, no RMW)
            const int half = l >> 3;
            #pragma unroll
            for (int p = 0; p < TPPT; ++p) {
                int idx = base + p * TBLOCK + tid;
                if (idx < B) {
                    float* po = out + (size_t)idx * (2*NLEV) + half * 16;
                    #pragma unroll
                    for (int q = 0; q < 4; ++q) {
                        float4 v;
                        v.x = o[p][4*q+0]; v.y = o[p][4*q+1];
                        v.z = o[p][4*q+2]; v.w = o[p][4*q+3];
                        ((float4*)po)[q] = v;
                    }
                }
            }
        }

        asm volatile("s_barrier" ::: "memory");   // protect buf before reuse
    }
}

// ---- safe no-workspace fallback: direct global gather ----------------------
__global__ __launch_bounds__(256) void mrhe_direct(
    const float* __restrict__ x,
    const float* __restrict__ tables,
    float* __restrict__ out,
    ResArr res, int B)
{
    int i = blockIdx.x * blockDim.x + threadIdx.x;
    if (i >= B) return;
    float px = x[3*(size_t)i+0], py = x[3*(size_t)i+1], pz = x[3*(size_t)i+2];
    float ax = 1.0f - px, ay = 1.0f - py, az = 1.0f - pz;
    float cw[8] = {(ax*ay)*az,(px*ay)*az,(px*py)*az,(ax*py)*az,
                   (ax*ay)*pz,(px*ay)*pz,(px*py)*pz,(ax*py)*pz};
    const uint32_t P1 = 2654435761u, P2 = 805459861u, m = TABLE_SZ - 1u;
    float o[2*NLEV];
    #pragma unroll
    for (int l = 0; l < NLEV; ++l) {
        float r = res.r[l];
        float sx = r*px, sy = r*py, sz = r*pz;
        uint32_t lx = (uint32_t)sx, hx = (uint32_t)ceilf(sx);
        uint32_t ly = (uint32_t)sy, hy = (uint32_t)ceilf(sy);
        uint32_t lz = (uint32_t)sz, hz = (uint32_t)ceilf(sz);
        uint32_t yl = P1*ly, yh = P1*hy, zl = P2*lz, zh = P2*hz;
        uint32_t h[8] = {(lx^yl^zl)&m,(hx^yl^zl)&m,(hx^yh^zl)&m,(lx^yh^zl)&m,
                         (lx^yl^zh)&m,(hx^yl^zh)&m,(hx^yh^zh)&m,(lx^yh^zh)&m};
        const float2* tbl = (const float2*)tables + (size_t)l * TABLE_SZ;
        float a0 = 0.f, a1 = 0.f;
        #pragma unroll
        for (int k = 0; k < 8; ++k) {
            float2 f = tbl[h[k]];
            a0 += f.x * cw[k]; a1 += f.y * cw[k];
        }
        o[2*l+0] = a0; o[2*l+1] = a1;
    }
    float4* po = (float4*)(out + (size_t)i * (2*NLEV));
    #pragma unroll
    for (int q = 0; q < (2*NLEV)/4; ++q) {
        float4 v; v.x = o[4*q+0]; v.y = o[4*q+1]; v.z = o[4*q+2]; v.w = o[4*q+3];
        po[q] = v;
    }
}

extern "C" void kernel_launch(void* const* d_in, const int* in_sizes, int n_in,
                              void* d_out, int out_size, void* d_ws, size_t ws_size,
                              hipStream_t stream)
{
    const float* x      = (const float*)d_in[0];
    const float* tables = (const float*)d_in[1];
    float* out = (float*)d_out;
    int B = in_sizes[0] / 3;

    // b = exp((log(512)-log(16))/15); res_l = floor(16 * b**l)  (host libm)
    ResArr res;
    float bgrow = expf((logf(512.0f) - logf(16.0f)) / 15.0f);
    for (int l = 0; l < NLEV; ++l)
        res.r[l] = floorf(16.0f * powf(bgrow, (float)l));

    const int n_entries = NLEV * TABLE_SZ;
    const size_t need = (size_t)n_entries * 4;          // 1 MiB packed fp16x2

    if (ws_size >= need && d_ws) {
        uint32_t* tb = (uint32_t*)d_ws;
        hipLaunchKernelGGL(cvt_tables, dim3(n_entries/4/256), dim3(256), 0, stream,
                           tables, tb, n_entries);

        // Proven best shape (r12/r15): 512-thr, PPT=2. Spill guard falls back
        // to 256-thr/PPT=4 (capture-safe host query, deterministic).
        hipFuncAttributes attr{};
        hipError_t e = hipFuncGetAttributes(&attr, (const void*)mrhe_db<512, 2>);
        bool use512 = (e == hipSuccess) && (attr.localSizeBytes == 0);

        if (use512) {
            int per_block = 512 * 2;
            int grid = (B + per_block - 1) / per_block;
            hipLaunchKernelGGL((mrhe_db<512, 2>), dim3(grid), dim3(512), 0, stream,
                               x, tb, out, res, B);
        } else {
            int per_block = 256 * 4;
            int grid = (B + per_block - 1) / per_block;
            hipLaunchKernelGGL((mrhe_db<256, 4>), dim3(grid), dim3(256), 0, stream,
                               x, tb, out, res, B);
        }
    } else {
        int grid = (B + 255) / 256;
        hipLaunchKernelGGL(mrhe_direct, dim3(grid), dim3(256), 0, stream,
                           x, tables, out, res, B);
    }
}